// Round 11
// baseline (284.636 us; speedup 1.0000x reference)
//
#include <hip/hip_runtime.h>

#define BSZ 8192
#define DIM 128
#define NLAB 1024
#define MARGIN 0.3f
#define EPS 1e-8f
#define NJ 32              // real j-splits
#define NJD 48             // diagnostic j-splits (1.5x work, OOB-safe scratch reads)
#define JCHUNK 256
#define NPH 8              // phases per block (32 cols each)

typedef __bf16 bf16x8 __attribute__((ext_vector_type(8)));
typedef float f32x4 __attribute__((ext_vector_type(4)));

#define AS1 __attribute__((address_space(1)))
#define AS3 __attribute__((address_space(3)))

__device__ __forceinline__ unsigned enc_ord(float f) {
    unsigned u = __float_as_uint(f);
    return (u & 0x80000000u) ? ~u : (u | 0x80000000u);
}
__device__ __forceinline__ float dec_ord(unsigned e) {
    unsigned u = (e & 0x80000000u) ? (e & 0x7FFFFFFFu) : ~e;
    return __uint_as_float(u);
}

template <int N>
__device__ __forceinline__ void waitv() {
    if constexpr (N == 2) asm volatile("s_waitcnt vmcnt(2)" ::: "memory");
    else asm volatile("s_waitcnt vmcnt(0)" ::: "memory");
}

// ---- histogram + scan (1 block) + one-time inits ----
__global__ __launch_bounds__(1024) void k_histscan(const int* __restrict__ labels,
                                                   unsigned* __restrict__ start,
                                                   unsigned* __restrict__ offset,
                                                   unsigned* __restrict__ ticket,
                                                   float* __restrict__ sumcnt) {
    __shared__ unsigned h[NLAB];
    const int tid = threadIdx.x;
    h[tid] = 0u;
    __syncthreads();
    const int4* l4 = (const int4*)labels;
    int4 a = l4[tid];
    int4 b = l4[tid + 1024];
    atomicAdd(&h[a.x], 1u); atomicAdd(&h[a.y], 1u);
    atomicAdd(&h[a.z], 1u); atomicAdd(&h[a.w], 1u);
    atomicAdd(&h[b.x], 1u); atomicAdd(&h[b.y], 1u);
    atomicAdd(&h[b.z], 1u); atomicAdd(&h[b.w], 1u);
    __syncthreads();
    for (int d = 1; d < NLAB; d <<= 1) {
        unsigned w = (tid >= d) ? h[tid - d] : 0u;
        __syncthreads();
        h[tid] += w;
        __syncthreads();
    }
    start[tid + 1] = h[tid];
    offset[tid] = (tid > 0) ? h[tid - 1] : 0u;
    if (tid == 0) {
        start[0] = 0u;
        ticket[0] = 0u;
        sumcnt[0] = 0.0f;
        ((unsigned*)sumcnt)[1] = 0u;
    }
}

// fused scatter + gather + convert + norms + min-init
__global__ __launch_bounds__(256) void k_gather(const float* __restrict__ emb,
                                                const int* __restrict__ labels,
                                                unsigned* __restrict__ offset,
                                                __bf16* __restrict__ hi,
                                                float* __restrict__ sq,
                                                int* __restrict__ slab,
                                                unsigned* __restrict__ minn) {
    int row = blockIdx.x * 4 + (threadIdx.x >> 6);
    int lane = threadIdx.x & 63;
    int lab = labels[row];
    unsigned pos = 0;
    if (lane == 0) pos = atomicAdd(&offset[lab], 1u);
    pos = __shfl(pos, 0);
    float2 v = *(const float2*)&emb[(size_t)row * DIM + lane * 2];
    union { __bf16 b[2]; unsigned u; } p;
    p.b[0] = (__bf16)v.x;
    p.b[1] = (__bf16)v.y;
    ((unsigned*)hi)[pos * 64 + lane] = p.u;
    float s = v.x * v.x + v.y * v.y;
#pragma unroll
    for (int m = 32; m >= 1; m >>= 1) s += __shfl_xor(s, m);
    if (lane == 0) {
        sq[pos] = s;
        slab[pos] = lab;
        minn[pos] = 0xFFFFFFFFu;
    }
}

// MODE 0: full (real). MODE 1: noDS (dummy B regs; staging/sync/epilogue kept).
// MODE 2: noBar (no waitv/s_barrier in loop; reads may be stale -> scratch only).
template <int MODE>
__global__ __launch_bounds__(256, 5) void k_mfmaD(const __bf16* __restrict__ hi,
                                                  const int* __restrict__ slab,
                                                  const unsigned* __restrict__ startp,
                                                  const float* __restrict__ sq,
                                                  unsigned* __restrict__ minn) {
    __shared__ char Bst[3][8][1024];
    __shared__ float sqlds[JCHUNK];

    const int tid = threadIdx.x;
    const int lane = tid & 63;
    const int wave = tid >> 6;
    const int lr = lane & 15;
    const int lq = lane >> 4;
    const int i0 = blockIdx.x * 128;
    const int it0 = i0 + wave * 32;
    const int j0 = blockIdx.y * JCHUNK;
    const float INF = __uint_as_float(0x7F800000u);

    const int lf = slab[i0];
    const int ll = slab[i0 + 127];
    const int blo = (int)startp[lf];
    const int bhi = (int)startp[ll + 1];
    unsigned mmask = 0;
#pragma unroll
    for (int tt = 0; tt < NPH; ++tt) {
        int c0 = j0 + tt * 32;
        if (bhi > c0 && blo < c0 + 32) mmask |= (1u << tt);
    }

    sqlds[tid] = sq[j0 + tid];

    bf16x8 a0[4], a1[4];
    const __bf16* ap = hi + (size_t)(it0 + lr) * DIM + lq * 8;
#pragma unroll
    for (int f = 0; f < 4; ++f) {
        a0[f] = *(const bf16x8*)&ap[f * 32];
        a1[f] = *(const bf16x8*)&ap[16 * DIM + f * 32];
        asm volatile("" : "+v"(a0[f]));
        asm volatile("" : "+v"(a1[f]));
    }

    int s0i[2][4], s1i[2][4];
#pragma unroll
    for (int it = 0; it < 2; ++it)
#pragma unroll
        for (int r = 0; r < 4; ++r) {
            int li = slab[it0 + it * 16 + lq * 4 + r];
            s0i[it][r] = (int)startp[li];
            s1i[it][r] = (int)startp[li + 1];
        }

    float mn[2][4];
#pragma unroll
    for (int it = 0; it < 2; ++it)
#pragma unroll
        for (int r = 0; r < 4; ++r) mn[it][r] = INF;

    const int m0 = wave * 2, m1 = m0 + 1;
    const __bf16* bsA = hi + (size_t)(j0 + (m0 >> 2) * 16 + lr) * DIM + (m0 & 3) * 32 + lq * 8;
    const __bf16* bsB = hi + (size_t)(j0 + (m1 >> 2) * 16 + lr) * DIM + (m1 & 3) * 32 + lq * 8;
#define STAGE(t, buf)                                                              \
    do {                                                                           \
        __builtin_amdgcn_global_load_lds(                                          \
            (const AS1 void*)(bsA + (size_t)(t) * 32 * DIM),                       \
            (AS3 void*)&Bst[buf][m0][0], 16, 0, 0);                                \
        __builtin_amdgcn_global_load_lds(                                          \
            (const AS1 void*)(bsB + (size_t)(t) * 32 * DIM),                       \
            (AS3 void*)&Bst[buf][m1][0], 16, 0, 0);                                \
    } while (0)

    STAGE(0, 0);
    STAGE(1, 1);
    __syncthreads();

#pragma unroll 1
    for (int t = 0; t < NPH; ++t) {
        if constexpr (MODE != 2) {
            if (t < NPH - 1) waitv<2>();
            else waitv<0>();
            __builtin_amdgcn_s_barrier();
            __builtin_amdgcn_sched_barrier(0);
        }
        if (t + 2 < NPH) STAGE(t + 2, (t + 2) % 3);

        const float sqj0 = sqlds[t * 32 + lr];
        const float sqj1 = sqlds[t * 32 + 16 + lr];

        const bf16x8* bp = (const bf16x8*)&Bst[t % 3][0][0];
        f32x4 acc00 = {0, 0, 0, 0}, acc01 = {0, 0, 0, 0};
        f32x4 acc10 = {0, 0, 0, 0}, acc11 = {0, 0, 0, 0};
#pragma unroll
        for (int f = 0; f < 4; ++f) {
            bf16x8 b0, b1;
            if constexpr (MODE == 1) {   // noDS: dummy register operands
                b0 = a0[f];
                b1 = a1[f];
            } else {
                b0 = bp[f * 64 + lane];
                b1 = bp[(4 + f) * 64 + lane];
            }
            acc00 = __builtin_amdgcn_mfma_f32_16x16x32_bf16(a0[f], b0, acc00, 0, 0, 0);
            acc10 = __builtin_amdgcn_mfma_f32_16x16x32_bf16(a1[f], b0, acc10, 0, 0, 0);
            acc01 = __builtin_amdgcn_mfma_f32_16x16x32_bf16(a0[f], b1, acc01, 0, 0, 0);
            acc11 = __builtin_amdgcn_mfma_f32_16x16x32_bf16(a1[f], b1, acc11, 0, 0, 0);
        }

        if (mmask & (1u << t)) {
            const int jj0 = j0 + t * 32 + lr;
            const int jj1 = jj0 + 16;
#pragma unroll
            for (int r = 0; r < 4; ++r) {
                float k00 = fmaf(-2.0f, acc00[r], sqj0);
                float k01 = fmaf(-2.0f, acc01[r], sqj1);
                float k10 = fmaf(-2.0f, acc10[r], sqj0);
                float k11 = fmaf(-2.0f, acc11[r], sqj1);
                bool o00 = (jj0 < s0i[0][r]) || (jj0 >= s1i[0][r]);
                bool o01 = (jj1 < s0i[0][r]) || (jj1 >= s1i[0][r]);
                bool o10 = (jj0 < s0i[1][r]) || (jj0 >= s1i[1][r]);
                bool o11 = (jj1 < s0i[1][r]) || (jj1 >= s1i[1][r]);
                mn[0][r] = o00 ? fminf(mn[0][r], k00) : mn[0][r];
                mn[0][r] = o01 ? fminf(mn[0][r], k01) : mn[0][r];
                mn[1][r] = o10 ? fminf(mn[1][r], k10) : mn[1][r];
                mn[1][r] = o11 ? fminf(mn[1][r], k11) : mn[1][r];
            }
        } else {
#pragma unroll
            for (int r = 0; r < 4; ++r) {
                float k00 = fmaf(-2.0f, acc00[r], sqj0);
                float k01 = fmaf(-2.0f, acc01[r], sqj1);
                float k10 = fmaf(-2.0f, acc10[r], sqj0);
                float k11 = fmaf(-2.0f, acc11[r], sqj1);
                mn[0][r] = fminf(mn[0][r], fminf(k00, k01));
                mn[1][r] = fminf(mn[1][r], fminf(k10, k11));
            }
        }
    }
#undef STAGE

#pragma unroll
    for (int m = 1; m < 16; m <<= 1)
#pragma unroll
        for (int it = 0; it < 2; ++it)
#pragma unroll
            for (int r = 0; r < 4; ++r)
                mn[it][r] = fminf(mn[it][r], __shfl_xor(mn[it][r], m));
    if (lr == 0) {
#pragma unroll
        for (int it = 0; it < 2; ++it)
#pragma unroll
            for (int r = 0; r < 4; ++r)
                atomicMin(&minn[it0 + it * 16 + lq * 4 + r], enc_ord(mn[it][r]));
    }
}

// hardest-positive, group-parallel: 4 j's per wave-iteration (16 lanes per dot)
__global__ __launch_bounds__(256) void k_final(const __bf16* __restrict__ hi,
                                               const int* __restrict__ slab,
                                               const unsigned* __restrict__ startp,
                                               const float* __restrict__ sq,
                                               const unsigned* __restrict__ minn,
                                               float* __restrict__ sumcnt,
                                               unsigned* __restrict__ ticket,
                                               float* __restrict__ out) {
    const int wave = threadIdx.x >> 6;
    const int lane = threadIdx.x & 63;
    const int grp = lane >> 4;
    const int lr = lane & 15;
    const int i = blockIdx.x * 4 + wave;
    const int lab = slab[i];
    const int s0 = (int)startp[lab];
    const int s1 = (int)startp[lab + 1];
    const uint4* h128 = (const uint4*)hi;   // row = 16 uint4
    uint4 ua = h128[(size_t)i * 16 + lr];
    float ax[8];
    ax[0] = __uint_as_float(ua.x << 16); ax[1] = __uint_as_float(ua.x & 0xFFFF0000u);
    ax[2] = __uint_as_float(ua.y << 16); ax[3] = __uint_as_float(ua.y & 0xFFFF0000u);
    ax[4] = __uint_as_float(ua.z << 16); ax[5] = __uint_as_float(ua.z & 0xFFFF0000u);
    ax[6] = __uint_as_float(ua.w << 16); ax[7] = __uint_as_float(ua.w & 0xFFFF0000u);
    const float sqi = sq[i];
    float mp2 = -3.0e38f;
    for (int base = s0; base < s1; base += 4) {
        int j = base + grp;
        bool ok = (j < s1) && (j != i);
        int jc = ok ? j : i;
        uint4 ub = h128[(size_t)jc * 16 + lr];
        float p;
        p  = ax[0] * __uint_as_float(ub.x << 16);
        p  = fmaf(ax[1], __uint_as_float(ub.x & 0xFFFF0000u), p);
        p  = fmaf(ax[2], __uint_as_float(ub.y << 16), p);
        p  = fmaf(ax[3], __uint_as_float(ub.y & 0xFFFF0000u), p);
        p  = fmaf(ax[4], __uint_as_float(ub.z << 16), p);
        p  = fmaf(ax[5], __uint_as_float(ub.z & 0xFFFF0000u), p);
        p  = fmaf(ax[6], __uint_as_float(ub.w << 16), p);
        p  = fmaf(ax[7], __uint_as_float(ub.w & 0xFFFF0000u), p);
#pragma unroll
        for (int m = 1; m <= 8; m <<= 1) p += __shfl_xor(p, m);
        float d2 = fmaf(-2.0f, p, sqi + sq[jc]);
        mp2 = ok ? fmaxf(mp2, d2) : mp2;
    }
    mp2 = fmaxf(mp2, __shfl_xor(mp2, 16));
    mp2 = fmaxf(mp2, __shfl_xor(mp2, 32));

    unsigned mnk = minn[i];
    float d2n = sqi + dec_ord(mnk);
    bool valid = ((s1 - s0) > 1) && (mnk != 0xFFFFFFFFu);
    float hp = sqrtf(fmaxf(mp2, 0.0f) + EPS);
    float hn = sqrtf(fmaxf(d2n, 0.0f) + EPS);
    float per = valid ? fmaxf(hp - hn + MARGIN, 0.0f) : 0.0f;

    __shared__ float ssum[4];
    __shared__ unsigned scnt[4];
    if (lane == 0) { ssum[wave] = per; scnt[wave] = valid ? 1u : 0u; }
    __syncthreads();
    if (threadIdx.x == 0) {
        float s = ssum[0] + ssum[1] + ssum[2] + ssum[3];
        unsigned c = scnt[0] + scnt[1] + scnt[2] + scnt[3];
        atomicAdd(&sumcnt[0], s);
        atomicAdd((unsigned*)&sumcnt[1], c);
        __threadfence();
        unsigned done = atomicAdd(ticket, 1u);
        if (done == gridDim.x - 1) {
            float ts = atomicAdd(&sumcnt[0], 0.0f);
            unsigned tc = atomicAdd((unsigned*)&sumcnt[1], 0u);
            out[0] = ts / (float)(tc > 0u ? tc : 1u);
        }
    }
}

extern "C" void kernel_launch(void* const* d_in, const int* in_sizes, int n_in,
                              void* d_out, int out_size, void* d_ws, size_t ws_size,
                              hipStream_t stream) {
    const float* emb    = (const float*)d_in[0];
    const int*   labels = (const int*)d_in[1];

    float* wsf = (float*)d_ws;
    __bf16*   hi     = (__bf16*)wsf;                       // [0, 524288)
    float*    sq     = wsf + 524288;                       // 8192
    unsigned* minn   = (unsigned*)(wsf + 532480);          // 8192
    float*    sumcnt = wsf + 540672;                       // 4
    unsigned* start  = (unsigned*)(wsf + 540676);          // 1025 (pad 1028)
    unsigned* offset = (unsigned*)(wsf + 541704);          // 1024
    unsigned* ticket = (unsigned*)(wsf + 542728);          // 1
    int*      slab   = (int*)(wsf + 542732);               // 8192
    unsigned* minn2  = (unsigned*)(wsf + 552960);          // 8192 diag scratch
    float*    out    = (float*)d_out;

    // ---- real chain ----
    k_histscan<<<dim3(1), dim3(1024), 0, stream>>>(labels, start, offset, ticket, sumcnt);
    k_gather<<<dim3(BSZ / 4), dim3(256), 0, stream>>>(emb, labels, offset, hi, sq, slab, minn);
    k_mfmaD<0><<<dim3(BSZ / 128, NJ), dim3(256), 0, stream>>>(hi, slab, start, sq, minn);
    k_final<<<dim3(BSZ / 4), dim3(256), 0, stream>>>(hi, slab, start, sq, minn, sumcnt, ticket, out);

    // ---- diagnostic dispatches (scratch output, 1.5x work for top-5 visibility) ----
    k_mfmaD<0><<<dim3(BSZ / 128, NJD), dim3(256), 0, stream>>>(hi, slab, start, sq, minn2);
    k_mfmaD<1><<<dim3(BSZ / 128, NJD), dim3(256), 0, stream>>>(hi, slab, start, sq, minn2);
    k_mfmaD<2><<<dim3(BSZ / 128, NJD), dim3(256), 0, stream>>>(hi, slab, start, sq, minn2);
}

// Round 12
// 57.352 us; speedup vs baseline: 4.9630x; 4.9630x over previous
//
#include <hip/hip_runtime.h>

#define BSZ 8192
#define DIM 128
#define NLAB 1024
#define MARGIN 0.3f
#define EPS 1e-8f
#define BM 256             // anchors per block
#define BJ 256             // j-cols per block
#define NIT 4              // i-tiles (16 rows) per wave
#define NJT 16             // j-tiles per block

typedef __bf16 bf16x8 __attribute__((ext_vector_type(8)));
typedef float f32x4 __attribute__((ext_vector_type(4)));

#define AS1 __attribute__((address_space(1)))
#define AS3 __attribute__((address_space(3)))

__device__ __forceinline__ unsigned enc_ord(float f) {
    unsigned u = __float_as_uint(f);
    return (u & 0x80000000u) ? ~u : (u | 0x80000000u);
}
__device__ __forceinline__ float dec_ord(unsigned e) {
    unsigned u = (e & 0x80000000u) ? (e & 0x7FFFFFFFu) : ~e;
    return __uint_as_float(u);
}

// ---- histogram + scan (1 block) ----
__global__ __launch_bounds__(1024) void k_histscan(const int* __restrict__ labels,
                                                   unsigned* __restrict__ start,
                                                   unsigned* __restrict__ offset) {
    __shared__ unsigned h[NLAB];
    const int tid = threadIdx.x;
    h[tid] = 0u;
    __syncthreads();
    const int4* l4 = (const int4*)labels;
    int4 a = l4[tid];
    int4 b = l4[tid + 1024];
    atomicAdd(&h[a.x], 1u); atomicAdd(&h[a.y], 1u);
    atomicAdd(&h[a.z], 1u); atomicAdd(&h[a.w], 1u);
    atomicAdd(&h[b.x], 1u); atomicAdd(&h[b.y], 1u);
    atomicAdd(&h[b.z], 1u); atomicAdd(&h[b.w], 1u);
    __syncthreads();
    for (int d = 1; d < NLAB; d <<= 1) {
        unsigned w = (tid >= d) ? h[tid - d] : 0u;
        __syncthreads();
        h[tid] += w;
        __syncthreads();
    }
    start[tid + 1] = h[tid];
    offset[tid] = (tid > 0) ? h[tid - 1] : 0u;
    if (tid == 0) start[0] = 0u;
}

// fused scatter + gather + convert + norms + min-init
__global__ __launch_bounds__(256) void k_gather(const float* __restrict__ emb,
                                                const int* __restrict__ labels,
                                                unsigned* __restrict__ offset,
                                                __bf16* __restrict__ hi,
                                                float* __restrict__ sq,
                                                int* __restrict__ slab,
                                                unsigned* __restrict__ minn) {
    int row = blockIdx.x * 4 + (threadIdx.x >> 6);
    int lane = threadIdx.x & 63;
    int lab = labels[row];
    unsigned pos = 0;
    if (lane == 0) pos = atomicAdd(&offset[lab], 1u);
    pos = __shfl(pos, 0);
    float2 v = *(const float2*)&emb[(size_t)row * DIM + lane * 2];
    union { __bf16 b[2]; unsigned u; } p;
    p.b[0] = (__bf16)v.x;
    p.b[1] = (__bf16)v.y;
    ((unsigned*)hi)[pos * 64 + lane] = p.u;
    float s = v.x * v.x + v.y * v.y;
#pragma unroll
    for (int m = 32; m >= 1; m >>= 1) s += __shfl_xor(s, m);
    if (lane == 0) {
        sq[pos] = s;
        slab[pos] = lab;
        minn[pos] = 0xFFFFFFFFu;
    }
}

// ONE-BARRIER main kernel: stage the whole 256x128 B-chunk into LDS, sync once,
// then every wave free-runs 16 j-tiles (4 ds_read_b128 -> 16 MFMA each) with no
// further synchronization. 4 waves x 64 anchors; A register-resident (64 VGPR).
__global__ __launch_bounds__(256, 2) void k_mfma(const __bf16* __restrict__ hi,
                                                 const int* __restrict__ slab,
                                                 const unsigned* __restrict__ startp,
                                                 const float* __restrict__ sq,
                                                 unsigned* __restrict__ minn) {
    __shared__ char Bst[NJT][4][1024];   // 64 KB, fragment-ordered
    __shared__ float sqlds[BJ];

    const int tid = threadIdx.x;
    const int lane = tid & 63;
    const int wave = tid >> 6;
    const int lr = lane & 15;
    const int lq = lane >> 4;
    const int i0 = blockIdx.x * BM;
    const int it0 = i0 + wave * 64;
    const int j0 = blockIdx.y * BJ;
    const float INF = __uint_as_float(0x7F800000u);

    // block-level positive band (sorted labels => contiguous)
    const int blo = (int)startp[slab[i0]];
    const int bhi = (int)startp[slab[i0 + BM - 1] + 1];

    sqlds[tid] = sq[j0 + tid];

    // stage B-chunk: wave stages j-tiles [wave*4, wave*4+4), frags f in [0,4)
    // src per-lane: hi[(j0 + jt*16 + lr)*128 + f*32 + lq*8]; dst lane*16B linear
#pragma unroll
    for (int q = 0; q < 4; ++q) {
        const int jt = wave * 4 + q;
        const __bf16* bs = hi + (size_t)(j0 + jt * 16 + lr) * DIM + lq * 8;
#pragma unroll
        for (int f = 0; f < 4; ++f)
            __builtin_amdgcn_global_load_lds((const AS1 void*)(bs + f * 32),
                                             (AS3 void*)&Bst[jt][f][0], 16, 0, 0);
    }

    // A fragments: 4 i-tiles x 4 K-frags, register-resident, pinned
    bf16x8 a[NIT][4];
#pragma unroll
    for (int tile = 0; tile < NIT; ++tile) {
        const __bf16* ap = hi + (size_t)(it0 + tile * 16 + lr) * DIM + lq * 8;
#pragma unroll
        for (int f = 0; f < 4; ++f) {
            a[tile][f] = *(const bf16x8*)&ap[f * 32];
            asm volatile("" : "+v"(a[tile][f]));
        }
    }

    // per-anchor exclusion intervals, packed 16+16 bit (s0 | s1<<16)
    unsigned spack[NIT][4];
#pragma unroll
    for (int tile = 0; tile < NIT; ++tile)
#pragma unroll
        for (int r = 0; r < 4; ++r) {
            int li = slab[it0 + tile * 16 + lq * 4 + r];
            spack[tile][r] = startp[li] | (startp[li + 1] << 16);
        }

    float mn[NIT][4];
#pragma unroll
    for (int tile = 0; tile < NIT; ++tile)
#pragma unroll
        for (int r = 0; r < 4; ++r) mn[tile][r] = INF;

    __syncthreads();   // ONLY barrier: drains all global_load_lds + ds_writes

#pragma unroll 2
    for (int jt = 0; jt < NJT; ++jt) {
        bf16x8 b[4];
#pragma unroll
        for (int f = 0; f < 4; ++f)
            b[f] = ((const bf16x8*)&Bst[jt][f][0])[lane];

        f32x4 acc[NIT];
#pragma unroll
        for (int tile = 0; tile < NIT; ++tile) acc[tile] = (f32x4){0, 0, 0, 0};
#pragma unroll
        for (int f = 0; f < 4; ++f)
#pragma unroll
            for (int tile = 0; tile < NIT; ++tile)
                acc[tile] = __builtin_amdgcn_mfma_f32_16x16x32_bf16(a[tile][f], b[f],
                                                                    acc[tile], 0, 0, 0);

        const float sqj = sqlds[jt * 16 + lr];
        const int c0 = j0 + jt * 16;
        if (bhi > c0 && blo < c0 + 16) {   // band tile: interval exclusion
            const int jj = c0 + lr;
#pragma unroll
            for (int tile = 0; tile < NIT; ++tile)
#pragma unroll
                for (int r = 0; r < 4; ++r) {
                    float k = fmaf(-2.0f, acc[tile][r], sqj);
                    int s0 = (int)(spack[tile][r] & 0xFFFFu);
                    int s1 = (int)(spack[tile][r] >> 16);
                    bool ok = (jj < s0) || (jj >= s1);
                    mn[tile][r] = ok ? fminf(mn[tile][r], k) : mn[tile][r];
                }
        } else {   // pure-negative tile
#pragma unroll
            for (int tile = 0; tile < NIT; ++tile)
#pragma unroll
                for (int r = 0; r < 4; ++r)
                    mn[tile][r] = fminf(mn[tile][r], fmaf(-2.0f, acc[tile][r], sqj));
        }
    }

    // reduce over the 16 cols (lr)
#pragma unroll
    for (int m = 1; m < 16; m <<= 1)
#pragma unroll
        for (int tile = 0; tile < NIT; ++tile)
#pragma unroll
            for (int r = 0; r < 4; ++r)
                mn[tile][r] = fminf(mn[tile][r], __shfl_xor(mn[tile][r], m));
    if (lr == 0) {
#pragma unroll
        for (int tile = 0; tile < NIT; ++tile)
#pragma unroll
            for (int r = 0; r < 4; ++r)
                atomicMin(&minn[it0 + tile * 16 + lq * 4 + r], enc_ord(mn[tile][r]));
    }
}

// hardest-positive (group-parallel dots) -> per-anchor hinge; NO atomics.
__global__ __launch_bounds__(256) void k_final(const __bf16* __restrict__ hi,
                                               const int* __restrict__ slab,
                                               const unsigned* __restrict__ startp,
                                               const float* __restrict__ sq,
                                               const unsigned* __restrict__ minn,
                                               float* __restrict__ pvals) {
    const int wave = threadIdx.x >> 6;
    const int lane = threadIdx.x & 63;
    const int grp = lane >> 4;
    const int lr = lane & 15;
    const int i = blockIdx.x * 4 + wave;
    const int lab = slab[i];
    const int s0 = (int)startp[lab];
    const int s1 = (int)startp[lab + 1];
    const uint4* h128 = (const uint4*)hi;
    uint4 ua = h128[(size_t)i * 16 + lr];
    float ax[8];
    ax[0] = __uint_as_float(ua.x << 16); ax[1] = __uint_as_float(ua.x & 0xFFFF0000u);
    ax[2] = __uint_as_float(ua.y << 16); ax[3] = __uint_as_float(ua.y & 0xFFFF0000u);
    ax[4] = __uint_as_float(ua.z << 16); ax[5] = __uint_as_float(ua.z & 0xFFFF0000u);
    ax[6] = __uint_as_float(ua.w << 16); ax[7] = __uint_as_float(ua.w & 0xFFFF0000u);
    const float sqi = sq[i];
    float mp2 = -3.0e38f;
    for (int base = s0; base < s1; base += 4) {
        int j = base + grp;
        bool ok = (j < s1) && (j != i);
        int jc = ok ? j : i;
        uint4 ub = h128[(size_t)jc * 16 + lr];
        float p;
        p = ax[0] * __uint_as_float(ub.x << 16);
        p = fmaf(ax[1], __uint_as_float(ub.x & 0xFFFF0000u), p);
        p = fmaf(ax[2], __uint_as_float(ub.y << 16), p);
        p = fmaf(ax[3], __uint_as_float(ub.y & 0xFFFF0000u), p);
        p = fmaf(ax[4], __uint_as_float(ub.z << 16), p);
        p = fmaf(ax[5], __uint_as_float(ub.z & 0xFFFF0000u), p);
        p = fmaf(ax[6], __uint_as_float(ub.w << 16), p);
        p = fmaf(ax[7], __uint_as_float(ub.w & 0xFFFF0000u), p);
#pragma unroll
        for (int m = 1; m <= 8; m <<= 1) p += __shfl_xor(p, m);
        float d2 = fmaf(-2.0f, p, sqi + sq[jc]);
        mp2 = ok ? fmaxf(mp2, d2) : mp2;
    }
    mp2 = fmaxf(mp2, __shfl_xor(mp2, 16));
    mp2 = fmaxf(mp2, __shfl_xor(mp2, 32));

    unsigned mnk = minn[i];
    float d2n = sqi + dec_ord(mnk);
    bool valid = ((s1 - s0) > 1) && (mnk != 0xFFFFFFFFu);
    float hp = sqrtf(fmaxf(mp2, 0.0f) + EPS);
    float hn = sqrtf(fmaxf(d2n, 0.0f) + EPS);
    float per = fmaxf(hp - hn + MARGIN, 0.0f);
    if (lane == 0) pvals[i] = valid ? per : -1.0f;
}

// single-block sum: 1024 threads x 8 values, no global atomics anywhere
__global__ __launch_bounds__(1024) void k_sum(const float* __restrict__ pvals,
                                              float* __restrict__ out) {
    const int tid = threadIdx.x;
    const float4* p4 = (const float4*)pvals;
    float4 v0 = p4[tid * 2];
    float4 v1 = p4[tid * 2 + 1];
    float s = 0.0f;
    unsigned c = 0u;
    float vv[8] = {v0.x, v0.y, v0.z, v0.w, v1.x, v1.y, v1.z, v1.w};
#pragma unroll
    for (int k = 0; k < 8; ++k) {
        bool ok = vv[k] >= 0.0f;
        s += ok ? vv[k] : 0.0f;
        c += ok ? 1u : 0u;
    }
#pragma unroll
    for (int m = 32; m >= 1; m >>= 1) {
        s += __shfl_xor(s, m);
        c += __shfl_xor(c, m);
    }
    __shared__ float ssum[16];
    __shared__ unsigned scnt[16];
    int wid = tid >> 6;
    if ((tid & 63) == 0) { ssum[wid] = s; scnt[wid] = c; }
    __syncthreads();
    if (tid == 0) {
        float ts = 0.0f;
        unsigned tc = 0u;
#pragma unroll
        for (int w = 0; w < 16; ++w) { ts += ssum[w]; tc += scnt[w]; }
        out[0] = ts / (float)(tc > 0u ? tc : 1u);
    }
}

extern "C" void kernel_launch(void* const* d_in, const int* in_sizes, int n_in,
                              void* d_out, int out_size, void* d_ws, size_t ws_size,
                              hipStream_t stream) {
    const float* emb    = (const float*)d_in[0];
    const int*   labels = (const int*)d_in[1];

    // 4-byte-slot layout; hi = 8192*128 bf16 = 524288 slots
    float* wsf = (float*)d_ws;
    __bf16*   hi     = (__bf16*)wsf;                       // [0, 524288)
    float*    sq     = wsf + 524288;                       // 8192
    unsigned* minn   = (unsigned*)(wsf + 532480);          // 8192
    unsigned* start  = (unsigned*)(wsf + 540672);          // 1025 (pad to 1028)
    unsigned* offset = (unsigned*)(wsf + 541700);          // 1024
    int*      slab   = (int*)(wsf + 542724);               // 8192
    float*    pvals  = wsf + 550916;                       // 8192 (16B-aligned)
    float*    out    = (float*)d_out;

    k_histscan<<<dim3(1), dim3(1024), 0, stream>>>(labels, start, offset);
    k_gather<<<dim3(BSZ / 4), dim3(256), 0, stream>>>(emb, labels, offset, hi, sq, slab, minn);
    k_mfma<<<dim3(BSZ / BM, BSZ / BJ), dim3(256), 0, stream>>>(hi, slab, start, sq, minn);
    k_final<<<dim3(BSZ / 4), dim3(256), 0, stream>>>(hi, slab, start, sq, minn, pvals);
    k_sum<<<dim3(1), dim3(1024), 0, stream>>>(pvals, out);
}